// Round 1
// baseline (325.555 us; speedup 1.0000x reference)
//
#include <hip/hip_runtime.h>
#include <hip/hip_bf16.h>

#define Bq   32
#define Cq   64
#define NPq  192
#define NOq  72
#define PTS  (NPq * NOq)   // 13824
#define REGD 76
#define OUTD 79

typedef __attribute__((ext_vector_type(8))) short short8;
typedef __attribute__((ext_vector_type(4))) float float4v;

__device__ inline unsigned short f2bf(float x) {
    __hip_bfloat16 h = __float2bfloat16(x);
    return *reinterpret_cast<unsigned short*>(&h);
}
__device__ inline float bf2f(unsigned short u) {
    unsigned int x = ((unsigned int)u) << 16;
    float f;
    __builtin_memcpy(&f, &x, 4);
    return f;
}

// ---------------------------------------------------------------------------
// Phase 0 (once): build gated y-blended tables for ALL 3 stages.
// EXACT R8 form (measured best: 43.5us; R9/R10 "improvements" both regressed).
// tab[s][b][o][x][c] bf16, x in [0..W] (x=W replicates W-1), c innermost.
// o-major block index (o*96 + s*32+b) keeps each (s,b)'s blocks on one XCD.
// ---------------------------------------------------------------------------
__global__ __launch_bounds__(256) void build_tables_kernel(
    const float* __restrict__ f0,   // x2: H=10,W=25
    const float* __restrict__ f1,   // x1: H=20,W=50
    const float* __restrict__ f2,   // x0: H=40,W=100
    const float* __restrict__ lw,
    unsigned short* __restrict__ t0,
    unsigned short* __restrict__ t1,
    unsigned short* __restrict__ t2)
{
    __shared__ float sRow[64 * 101];

    const int tid = threadIdx.x;
    const int o   = blockIdx.x / 96;
    const int sb  = blockIdx.x - o * 96;
    const int s   = sb >> 5;
    const int b   = sb & 31;

    const float* feat; unsigned short* tab; int H, W;
    if (s == 0)      { feat = f0; tab = t0; H = 10; W = 25; }
    else if (s == 1) { feat = f1; tab = t1; H = 20; W = 50; }
    else             { feat = f2; tab = t2; H = 40; W = 100; }
    const int Wp = W + 1;

    const float ys = 1.0f - (float)o * (1.0f / 71.0f);
    const float iy = ys * (float)(H - 1);
    const float fy = floorf(iy);
    const float wy = iy - fy;
    int iy0 = (int)fy; iy0 = iy0 < 0 ? 0 : (iy0 > H - 1 ? H - 1 : iy0);
    const int iy1 = (iy0 + 1 > H - 1) ? H - 1 : iy0 + 1;
    const float gate = 1.0f / (1.0f + __expf(-lw[o]));

    const float* fb = feat + (size_t)b * 64 * H * W;
    const int iy0W = iy0 * W, iy1W = iy1 * W;

    // blend rows -> LDS [c][x] fp32
    const int tot = 64 * W;
    for (int idx = tid; idx < tot; idx += 256) {
        const int c = idx / W;
        const int x = idx - c * W;
        const float* f = fb + c * (H * W);
        sRow[c * Wp + x] = ((1.0f - wy) * f[iy0W + x] + wy * f[iy1W + x]) * gate;
    }
    __syncthreads();

    // write transposed [x][c] bf16 (c-major coalesced), pad x=W
    unsigned short* to = tab + (size_t)(b * NOq + o) * Wp * 64;
    const int tot2 = Wp * 64;
    for (int idx = tid; idx < tot2; idx += 256) {
        const int x = idx >> 6;
        const int c = idx & 63;
        const int xx = (x < W) ? x : (W - 1);
        to[idx] = f2bf(sRow[c * Wp + xx]);
    }
}

// ---------------------------------------------------------------------------
// Fused: table gather + MFMA with C-SPACE x-lerp + relu/pairmax/mean + HEAD.
// R11: head restructured to kill the LDS-issue bottleneck:
//  - weights read DIRECTLY from global (L1/L2-resident, shared by all blocks)
//    -> no sWt staging, no staging barriers (14 -> 7), LDS 28.1KB -> 8.7KB
//  - activation LDS reads explicitly vectorized (ds_read_b128 broadcasts)
// ---------------------------------------------------------------------------
template<int W>
__global__ __launch_bounds__(256) void fused_pool_head_kernel(
    const unsigned short* __restrict__ tab,   // [B][72][W+1][64] bf16
    const float* __restrict__ xsrc, const int xstride,
    const float* __restrict__ lsgi,           // [64][64] this stage
    float* __restrict__ sumFeat,              // [B*NP][64]
    const int stage,
    const float* __restrict__ fc_w,  const float* __restrict__ fc_b,
    const float* __restrict__ cls_w, const float* __restrict__ cls_b,
    const float* __restrict__ cls_ow, const float* __restrict__ cls_ob,
    const float* __restrict__ reg_w, const float* __restrict__ reg_b,
    const float* __restrict__ reg_ow, const float* __restrict__ reg_ob,
    const float* __restrict__ loc_w, const float* __restrict__ loc_b,
    const float* __restrict__ loc_ow, const float* __restrict__ loc_ob,
    float* __restrict__ out, float* __restrict__ xs_next)
{
    constexpr int Wp = W + 1;
    __shared__ __align__(16) float sF [8][68];
    __shared__ __align__(16) float sC [8][68];
    __shared__ __align__(16) float sT1[8][68];
    __shared__ __align__(16) float sT2[8][68];

    const int tid  = threadIdx.x;
    const int w    = tid >> 6;
    const int lane = tid & 63;
    const int ng   = blockIdx.x >> 5;         // 0..23
    const int b    = blockIdx.x & 31;
    const int npair = ng * 4 + w;             // 0..95

    // ---------------- pool (verbatim from best-measured version) ----------
    short8 wf[4][2];
    {
        const int kb = ((lane >> 4) & 3) * 8;
        const int dl = lane & 15;
        #pragma unroll
        for (int ks = 0; ks < 2; ++ks)
            #pragma unroll
            for (int dt = 0; dt < 4; ++dt) {
                union { unsigned short u[8]; short8 v; } pk;
                #pragma unroll
                for (int j = 0; j < 8; ++j)
                    pk.u[j] = f2bf(lsgi[(ks * 32 + kb + j) * 64 + dt * 16 + dl]);
                wf[dt][ks] = pk.v;
            }
    }

    const unsigned short* tb = tab + (size_t)b * NOq * Wp * 64;
    const float* xp = xsrc + (size_t)xstride * b;
    const int m  = lane & 15;
    const int kg = lane >> 4;
    const int nt0 = npair * 9;

    float sums0[4] = {0.f, 0.f, 0.f, 0.f};
    float sums1[4] = {0.f, 0.f, 0.f, 0.f};

    #pragma unroll
    for (int ntl = 0; ntl < 9; ++ntl) {
        const int pt = (nt0 + ntl) * 16 + m;
        const int o  = pt % NOq;
        float ixf = xp[pt] * (float)(W - 1);
        ixf = fminf(fmaxf(ixf, 0.0f), (float)(W - 1));
        const float fx = floorf(ixf);
        const float wx = ixf - fx;
        const int ix0 = (int)fx;

        const unsigned short* col = tb + ((size_t)o * Wp + ix0) * 64 + kg * 8;
        const short8 a00 = *(const short8*)(col);        // tap0, k-lo
        const short8 a01 = *(const short8*)(col + 64);   // tap1, k-lo
        const short8 a10 = *(const short8*)(col + 32);   // tap0, k-hi
        const short8 a11 = *(const short8*)(col + 96);   // tap1, k-hi

        // per-C-row wx (rows kg*4 .. kg*4+3 of this tile)
        float wxr[4];
        #pragma unroll
        for (int j = 0; j < 4; ++j) wxr[j] = __shfl(wx, kg * 4 + j);

        const bool hi = (ntl * 16 + (kg * 4)) >= NOq;
        #pragma unroll
        for (int dt = 0; dt < 4; ++dt) {
            float4v c0 = {0.f, 0.f, 0.f, 0.f};
            float4v c1 = {0.f, 0.f, 0.f, 0.f};
            c0 = __builtin_amdgcn_mfma_f32_16x16x32_bf16(a00, wf[dt][0], c0, 0, 0, 0);
            c0 = __builtin_amdgcn_mfma_f32_16x16x32_bf16(a10, wf[dt][1], c0, 0, 0, 0);
            c1 = __builtin_amdgcn_mfma_f32_16x16x32_bf16(a01, wf[dt][0], c1, 0, 0, 0);
            c1 = __builtin_amdgcn_mfma_f32_16x16x32_bf16(a11, wf[dt][1], c1, 0, 0, 0);
            const float v0 = c0[0] + wxr[0] * (c1[0] - c0[0]);
            const float v1 = c0[1] + wxr[1] * (c1[1] - c0[1]);
            const float v2 = c0[2] + wxr[2] * (c1[2] - c0[2]);
            const float v3 = c0[3] + wxr[3] * (c1[3] - c0[3]);
            const float pm0 = fmaxf(fmaxf(v0, v1), 0.f);
            const float pm1 = fmaxf(fmaxf(v2, v3), 0.f);
            const float add = pm0 + pm1;
            if (hi) sums1[dt] += add; else sums0[dt] += add;
        }
    }

    #pragma unroll
    for (int dt = 0; dt < 4; ++dt) {
        float v0 = sums0[dt], v1 = sums1[dt];
        v0 += __shfl_xor(v0, 16); v0 += __shfl_xor(v0, 32);
        v1 += __shfl_xor(v1, 16); v1 += __shfl_xor(v1, 32);
        sums0[dt] = v0; sums1[dt] = v1;
    }

    const float invS = 1.0f / (float)(stage + 1);
    if (lane < 16) {
        const size_t row0 = (size_t)(b * NPq + npair * 2) * 64;
        #pragma unroll
        for (int dt = 0; dt < 4; ++dt) {
            const int d = dt * 16 + lane;
            float t0 = sums0[dt] * (1.0f / 36.0f);
            float t1 = sums1[dt] * (1.0f / 36.0f);
            float* p0 = sumFeat + row0 + d;
            float* p1 = sumFeat + row0 + 64 + d;
            if (stage > 0) { t0 += *p0; t1 += *p1; }
            *p0 = t0; *p1 = t1;
            sF[2 * w][d]     = t0 * invS;
            sF[2 * w + 1][d] = t1 * invS;
        }
    }
    __syncthreads();   // sF ready for head

    // ---------------- head (8 points, in-block) ----------------
    // Weights come straight from global (L1/L2-hot); activations from LDS as
    // float4 broadcasts. Each gemm64 ends with its own barrier (dst ready +
    // WAR protection for the next layer's writes).
    const int pt2 = tid >> 5;          // 0..7 local point
    const int dh  = tid & 31;
    const int d0  = dh * 2;
    const int p0g = b * NPq + ng * 8;  // global point base

    auto gemm64 = [&](const float (*src)[68], float (*dst)[68],
                      const float* __restrict__ gw, const float* __restrict__ gb) {
        const float2 bb = *(const float2*)&gb[d0];
        float a0 = bb.x, a1 = bb.y;
        #pragma unroll 4
        for (int k = 0; k < 64; k += 4) {
            const float4v av = *(const float4v*)&src[pt2][k];
            const float2 w0 = *(const float2*)&gw[(k + 0) * 64 + d0];
            const float2 w1 = *(const float2*)&gw[(k + 1) * 64 + d0];
            const float2 w2 = *(const float2*)&gw[(k + 2) * 64 + d0];
            const float2 w3 = *(const float2*)&gw[(k + 3) * 64 + d0];
            a0 += av[0] * w0.x + av[1] * w1.x + av[2] * w2.x + av[3] * w3.x;
            a1 += av[0] * w0.y + av[1] * w1.y + av[2] * w2.y + av[3] * w3.y;
        }
        dst[pt2][d0]     = fmaxf(a0, 0.f);
        dst[pt2][d0 + 1] = fmaxf(a1, 0.f);
        __syncthreads();
    };

    gemm64(sF, sC, fc_w, fc_b);

    // ---- cls ----
    gemm64(sC,  sT1, cls_w,        cls_b);
    gemm64(sT1, sT2, cls_w + 4096, cls_b + 64);
    if (tid < 16) {
        const int p = tid >> 1, d = tid & 1;
        float z = cls_ob[d];
        #pragma unroll 4
        for (int k = 0; k < 64; k += 4) {
            const float4v av = *(const float4v*)&sT2[p][k];
            z += av[0] * cls_ow[(k + 0) * 2 + d] + av[1] * cls_ow[(k + 1) * 2 + d]
               + av[2] * cls_ow[(k + 2) * 2 + d] + av[3] * cls_ow[(k + 3) * 2 + d];
        }
        out[(size_t)(p0g + p) * OUTD + d] = z;
    }
    // (no barrier needed: sT2 readers finish before reg-gemm1's trailing
    //  barrier, and sT2 is only overwritten after that barrier by reg-gemm2)

    // ---- reg ----
    gemm64(sC,  sT1, reg_w,        reg_b);
    gemm64(sT1, sT2, reg_w + 4096, reg_b + 64);
    {
        float* orow = out + (size_t)(p0g + pt2) * OUTD;
        float* xsp  = xs_next + (size_t)(p0g + pt2) * NOq;
        for (int j = dh; j < REGD; j += 32) {
            float z = reg_ob[j];
            #pragma unroll 4
            for (int k = 0; k < 64; k += 4) {
                const float4v av = *(const float4v*)&sT2[pt2][k];
                z += av[0] * reg_ow[(k + 0) * REGD + j] + av[1] * reg_ow[(k + 1) * REGD + j]
                   + av[2] * reg_ow[(k + 2) * REGD + j] + av[3] * reg_ow[(k + 3) * REGD + j];
            }
            orow[2 + j] = z;
            if (j >= 4) xsp[j - 4] = 1.0f / (1.0f + __expf(-z));
        }
    }

    // ---- loc ----
    gemm64(sC,  sT1, loc_w,        loc_b);
    gemm64(sT1, sT2, loc_w + 4096, loc_b + 64);
    if (tid < 8) {
        float z = loc_ob[0];
        #pragma unroll 4
        for (int k = 0; k < 64; k += 4) {
            const float4v av = *(const float4v*)&sT2[tid][k];
            z += av[0] * loc_ow[k] + av[1] * loc_ow[k + 1]
               + av[2] * loc_ow[k + 2] + av[3] * loc_ow[k + 3];
        }
        out[(size_t)(p0g + tid) * OUTD + 78] = z;
    }
}

// ---------------------------------------------------------------------------
extern "C" void kernel_launch(void* const* d_in, const int* in_sizes, int n_in,
                              void* d_out, int out_size, void* d_ws, size_t ws_size,
                              hipStream_t stream)
{
    const float* x0        = (const float*)d_in[0];
    const float* x1        = (const float*)d_in[1];
    const float* x2        = (const float*)d_in[2];
    const float* prior_xs0 = (const float*)d_in[3];
    const float* l_weight  = (const float*)d_in[4];
    const float* lsgi_w    = (const float*)d_in[5];
    const float* fc_w      = (const float*)d_in[6];
    const float* fc_b      = (const float*)d_in[7];
    const float* cls_w     = (const float*)d_in[8];
    const float* cls_b     = (const float*)d_in[9];
    const float* cls_ow    = (const float*)d_in[10];
    const float* cls_ob    = (const float*)d_in[11];
    const float* reg_w     = (const float*)d_in[12];
    const float* reg_b     = (const float*)d_in[13];
    const float* reg_ow    = (const float*)d_in[14];
    const float* reg_ob    = (const float*)d_in[15];
    const float* loc_w     = (const float*)d_in[16];
    const float* loc_b     = (const float*)d_in[17];
    const float* loc_ow    = (const float*)d_in[18];
    const float* loc_ob    = (const float*)d_in[19];

    float* out     = (float*)d_out;
    float* sumFeat = (float*)d_ws;                               // [6144][64] f32
    float* xs      = sumFeat + (size_t)Bq * NPq * Cq;            // [6144][72] f32
    unsigned short* tab0 = (unsigned short*)(xs + (size_t)Bq * PTS);
    unsigned short* tab1 = tab0 + (size_t)Bq * NOq * 26  * 64;   // W=25
    unsigned short* tab2 = tab1 + (size_t)Bq * NOq * 51  * 64;   // W=50

    hipLaunchKernelGGL(build_tables_kernel, dim3(3 * Bq * NOq), dim3(256), 0, stream,
                       x2, x1, x0, l_weight, tab0, tab1, tab2);

    for (int s = 0; s < 3; ++s) {
        const float* xsrc = (s == 0) ? prior_xs0 : xs;
        const int xstr    = (s == 0) ? 0 : PTS;
        const unsigned short* tb = (s == 0) ? tab0 : (s == 1) ? tab1 : tab2;
        float* outS = out + (size_t)s * Bq * NPq * OUTD;
        if (s == 0)
            hipLaunchKernelGGL((fused_pool_head_kernel<25>), dim3(Bq * 24), dim3(256), 0, stream,
                               tb, xsrc, xstr, lsgi_w + s * 4096, sumFeat, s,
                               fc_w, fc_b, cls_w, cls_b, cls_ow, cls_ob,
                               reg_w, reg_b, reg_ow, reg_ob,
                               loc_w, loc_b, loc_ow, loc_ob, outS, xs);
        else if (s == 1)
            hipLaunchKernelGGL((fused_pool_head_kernel<50>), dim3(Bq * 24), dim3(256), 0, stream,
                               tb, xsrc, xstr, lsgi_w + s * 4096, sumFeat, s,
                               fc_w, fc_b, cls_w, cls_b, cls_ow, cls_ob,
                               reg_w, reg_b, reg_ow, reg_ob,
                               loc_w, loc_b, loc_ow, loc_ob, outS, xs);
        else
            hipLaunchKernelGGL((fused_pool_head_kernel<100>), dim3(Bq * 24), dim3(256), 0, stream,
                               tb, xsrc, xstr, lsgi_w + s * 4096, sumFeat, s,
                               fc_w, fc_b, cls_w, cls_b, cls_ow, cls_ob,
                               reg_w, reg_b, reg_ow, reg_ob,
                               loc_w, loc_b, loc_ow, loc_ob, outS, xs);
    }
}

// Round 3
// 317.651 us; speedup vs baseline: 1.0249x; 1.0249x over previous
//
#include <hip/hip_runtime.h>
#include <hip/hip_bf16.h>

#define Bq   32
#define Cq   64
#define NPq  192
#define NOq  72
#define PTS  (NPq * NOq)   // 13824
#define REGD 76
#define OUTD 79

typedef __attribute__((ext_vector_type(8))) short short8;
typedef __attribute__((ext_vector_type(4))) float float4v;

__device__ inline unsigned short f2bf(float x) {
    __hip_bfloat16 h = __float2bfloat16(x);
    return *reinterpret_cast<unsigned short*>(&h);
}

// ---------------------------------------------------------------------------
// Phase 0 (once): build gated y-blended tables for ALL 3 stages.
// EXACT R8 form (measured best; later variants regressed).
// tab[s][b][o][x][c] bf16, x in [0..W] (x=W replicates W-1), c innermost.
// ---------------------------------------------------------------------------
__global__ __launch_bounds__(256) void build_tables_kernel(
    const float* __restrict__ f0,   // x2: H=10,W=25
    const float* __restrict__ f1,   // x1: H=20,W=50
    const float* __restrict__ f2,   // x0: H=40,W=100
    const float* __restrict__ lw,
    unsigned short* __restrict__ t0,
    unsigned short* __restrict__ t1,
    unsigned short* __restrict__ t2)
{
    __shared__ float sRow[64 * 101];

    const int tid = threadIdx.x;
    const int o   = blockIdx.x / 96;
    const int sb  = blockIdx.x - o * 96;
    const int s   = sb >> 5;
    const int b   = sb & 31;

    const float* feat; unsigned short* tab; int H, W;
    if (s == 0)      { feat = f0; tab = t0; H = 10; W = 25; }
    else if (s == 1) { feat = f1; tab = t1; H = 20; W = 50; }
    else             { feat = f2; tab = t2; H = 40; W = 100; }
    const int Wp = W + 1;

    const float ys = 1.0f - (float)o * (1.0f / 71.0f);
    const float iy = ys * (float)(H - 1);
    const float fy = floorf(iy);
    const float wy = iy - fy;
    int iy0 = (int)fy; iy0 = iy0 < 0 ? 0 : (iy0 > H - 1 ? H - 1 : iy0);
    const int iy1 = (iy0 + 1 > H - 1) ? H - 1 : iy0 + 1;
    const float gate = 1.0f / (1.0f + __expf(-lw[o]));

    const float* fb = feat + (size_t)b * 64 * H * W;
    const int iy0W = iy0 * W, iy1W = iy1 * W;

    // blend rows -> LDS [c][x] fp32
    const int tot = 64 * W;
    for (int idx = tid; idx < tot; idx += 256) {
        const int c = idx / W;
        const int x = idx - c * W;
        const float* f = fb + c * (H * W);
        sRow[c * Wp + x] = ((1.0f - wy) * f[iy0W + x] + wy * f[iy1W + x]) * gate;
    }
    __syncthreads();

    // write transposed [x][c] bf16 (c-major coalesced), pad x=W
    unsigned short* to = tab + (size_t)(b * NOq + o) * Wp * 64;
    const int tot2 = Wp * 64;
    for (int idx = tid; idx < tot2; idx += 256) {
        const int x = idx >> 6;
        const int c = idx & 63;
        const int xx = (x < W) ? x : (W - 1);
        to[idx] = f2bf(sRow[c * Wp + xx]);
    }
}

// ---------------------------------------------------------------------------
// One stage: table gather + MFMA with C-space x-lerp + relu/pairmax/mean
// + head. VERBATIM R8 body (measured best: 44.5us/stage).
// Inter-stage state (xs sigmoid outputs, running feature sum) is BLOCK-
// PRIVATE -> lives in LDS (sXs, sSum); no grid sync, no global round-trip,
// no restrict aliasing. STAGE is a template param so the x-source read
// (prior_xs0 global vs sXs LDS) folds at compile time.
// ---------------------------------------------------------------------------
template<int W, int STAGE>
__device__ __forceinline__ void pool_head_stage(
    float (*sF)[68], float (*sC)[68], float (*sT1)[68], float (*sT2)[68],
    float* sWt, float (*sXs)[72], float (*sSum)[64],
    const unsigned short* __restrict__ tab,   // [B][72][W+1][64] bf16
    const float* __restrict__ prior0,         // stage-0 x source (global)
    const float* __restrict__ lsgi,           // [64][64] this stage
    const float* __restrict__ fc_w,  const float* __restrict__ fc_b,
    const float* __restrict__ cls_w, const float* __restrict__ cls_b,
    const float* __restrict__ cls_ow, const float* __restrict__ cls_ob,
    const float* __restrict__ reg_w, const float* __restrict__ reg_b,
    const float* __restrict__ reg_ow, const float* __restrict__ reg_ob,
    const float* __restrict__ loc_w, const float* __restrict__ loc_b,
    const float* __restrict__ loc_ow, const float* __restrict__ loc_ob,
    float* out)
{
    constexpr int Wp = W + 1;

    const int tid  = threadIdx.x;
    const int w    = tid >> 6;
    const int lane = tid & 63;
    const int ng   = blockIdx.x >> 5;         // 0..23
    const int b    = blockIdx.x & 31;
    const int npair = ng * 4 + w;             // 0..95

    // ---------------- pool ----------------
    short8 wf[4][2];
    {
        const int kb = ((lane >> 4) & 3) * 8;
        const int dl = lane & 15;
        #pragma unroll
        for (int ks = 0; ks < 2; ++ks)
            #pragma unroll
            for (int dt = 0; dt < 4; ++dt) {
                union { unsigned short u[8]; short8 v; } pk;
                #pragma unroll
                for (int j = 0; j < 8; ++j)
                    pk.u[j] = f2bf(lsgi[(ks * 32 + kb + j) * 64 + dt * 16 + dl]);
                wf[dt][ks] = pk.v;
            }
    }

    const unsigned short* tb = tab + (size_t)b * NOq * Wp * 64;
    const int m  = lane & 15;
    const int kg = lane >> 4;

    float sums0[4] = {0.f, 0.f, 0.f, 0.f};
    float sums1[4] = {0.f, 0.f, 0.f, 0.f};

    #pragma unroll
    for (int ntl = 0; ntl < 9; ++ntl) {
        // local (within-block) point-tile index: ptl in [0,576)
        const int ptl = (w * 9 + ntl) * 16 + m;
        const int o   = ptl % NOq;
        float xval;
        if (STAGE == 0) {
            xval = prior0[npair * 144 + ntl * 16 + m];   // = global pt, xstride 0
        } else {
            xval = sXs[ptl / NOq][o];
        }
        float ixf = xval * (float)(W - 1);
        ixf = fminf(fmaxf(ixf, 0.0f), (float)(W - 1));
        const float fx = floorf(ixf);
        const float wx = ixf - fx;
        const int ix0 = (int)fx;

        const unsigned short* col = tb + ((size_t)o * Wp + ix0) * 64 + kg * 8;
        const short8 a00 = *(const short8*)(col);        // tap0, k-lo
        const short8 a01 = *(const short8*)(col + 64);   // tap1, k-lo
        const short8 a10 = *(const short8*)(col + 32);   // tap0, k-hi
        const short8 a11 = *(const short8*)(col + 96);   // tap1, k-hi

        // per-C-row wx (rows kg*4 .. kg*4+3 of this tile)
        float wxr[4];
        #pragma unroll
        for (int j = 0; j < 4; ++j) wxr[j] = __shfl(wx, kg * 4 + j);

        const bool hi = (ntl * 16 + (kg * 4)) >= NOq;
        #pragma unroll
        for (int dt = 0; dt < 4; ++dt) {
            float4v c0 = {0.f, 0.f, 0.f, 0.f};
            float4v c1 = {0.f, 0.f, 0.f, 0.f};
            c0 = __builtin_amdgcn_mfma_f32_16x16x32_bf16(a00, wf[dt][0], c0, 0, 0, 0);
            c0 = __builtin_amdgcn_mfma_f32_16x16x32_bf16(a10, wf[dt][1], c0, 0, 0, 0);
            c1 = __builtin_amdgcn_mfma_f32_16x16x32_bf16(a01, wf[dt][0], c1, 0, 0, 0);
            c1 = __builtin_amdgcn_mfma_f32_16x16x32_bf16(a11, wf[dt][1], c1, 0, 0, 0);
            const float v0 = c0[0] + wxr[0] * (c1[0] - c0[0]);
            const float v1 = c0[1] + wxr[1] * (c1[1] - c0[1]);
            const float v2 = c0[2] + wxr[2] * (c1[2] - c0[2]);
            const float v3 = c0[3] + wxr[3] * (c1[3] - c0[3]);
            const float pm0 = fmaxf(fmaxf(v0, v1), 0.f);
            const float pm1 = fmaxf(fmaxf(v2, v3), 0.f);
            const float add = pm0 + pm1;
            if (hi) sums1[dt] += add; else sums0[dt] += add;
        }
    }

    #pragma unroll
    for (int dt = 0; dt < 4; ++dt) {
        float v0 = sums0[dt], v1 = sums1[dt];
        v0 += __shfl_xor(v0, 16); v0 += __shfl_xor(v0, 32);
        v1 += __shfl_xor(v1, 16); v1 += __shfl_xor(v1, 32);
        sums0[dt] = v0; sums1[dt] = v1;
    }

    constexpr float invS = 1.0f / (float)(STAGE + 1);
    if (lane < 16) {
        #pragma unroll
        for (int dt = 0; dt < 4; ++dt) {
            const int d = dt * 16 + lane;
            float t0 = sums0[dt] * (1.0f / 36.0f);
            float t1 = sums1[dt] * (1.0f / 36.0f);
            if (STAGE > 0) { t0 += sSum[2 * w][d]; t1 += sSum[2 * w + 1][d]; }
            sSum[2 * w][d]     = t0;            // same thread touches same slot
            sSum[2 * w + 1][d] = t1;            // every stage -> no barrier needed
            sF[2 * w][d]     = t0 * invS;
            sF[2 * w + 1][d] = t1 * invS;
        }
    }

    // ---------------- head (8 points, in-block; verbatim R8) ----------------
    const int pt2 = tid >> 5;          // 0..7 local point
    const int dh  = tid & 31;
    const int d0  = dh * 2;
    const int p0g = b * NPq + ng * 8;  // global point base

    auto gemm64 = [&](const float (*src)[68], float (*dst)[68],
                      const float* __restrict__ gw, const float* __restrict__ gb) {
        __syncthreads();
        #pragma unroll
        for (int i = 0; i < 4; ++i)
            *(float4*)&sWt[(i * 256 + tid) * 4] = *(const float4*)&gw[(i * 256 + tid) * 4];
        __syncthreads();
        float a0 = gb[d0], a1 = gb[d0 + 1];
        #pragma unroll 8
        for (int k = 0; k < 64; ++k) {
            const float av = src[pt2][k];
            const float2 w2 = *(const float2*)&sWt[k * 64 + d0];
            a0 += av * w2.x; a1 += av * w2.y;
        }
        dst[pt2][d0]     = fmaxf(a0, 0.f);
        dst[pt2][d0 + 1] = fmaxf(a1, 0.f);
    };

    gemm64(sF, sC, fc_w, fc_b);

    // ---- cls ----
    gemm64(sC,  sT1, cls_w,        cls_b);
    gemm64(sT1, sT2, cls_w + 4096, cls_b + 64);
    __syncthreads();
    if (tid < 16) {
        const int p = tid >> 1, d = tid & 1;
        float z = cls_ob[d];
        #pragma unroll 8
        for (int k = 0; k < 64; ++k) z += sT2[p][k] * cls_ow[k * 2 + d];
        out[(size_t)(p0g + p) * OUTD + d] = z;
    }

    // ---- reg ----
    gemm64(sC,  sT1, reg_w,        reg_b);
    gemm64(sT1, sT2, reg_w + 4096, reg_b + 64);
    __syncthreads();
    for (int idx = tid; idx < 64 * REGD; idx += 256) sWt[idx] = reg_ow[idx];
    __syncthreads();
    {
        float* orow = out + (size_t)(p0g + pt2) * OUTD;
        for (int j = dh; j < REGD; j += 32) {
            float z = reg_ob[j];
            #pragma unroll 8
            for (int k = 0; k < 64; ++k) z += sT2[pt2][k] * sWt[k * REGD + j];
            orow[2 + j] = z;
            if (j >= 4) sXs[pt2][j - 4] = 1.0f / (1.0f + __expf(-z));
        }
    }

    // ---- loc ----
    gemm64(sC,  sT1, loc_w,        loc_b);
    gemm64(sT1, sT2, loc_w + 4096, loc_b + 64);
    __syncthreads();
    if (tid < 8) {
        float z = loc_ob[0];
        #pragma unroll 8
        for (int k = 0; k < 64; ++k) z += sT2[tid][k] * loc_ow[k];
        out[(size_t)(p0g + tid) * OUTD + 78] = z;
    }
}

// ---------------------------------------------------------------------------
// All three stages chained in ONE PLAIN kernel. No grid sync needed: every
// inter-stage dependency is block-private (block (ng,b) reads only the 8
// points it wrote). Inter-stage state carried in LDS.
// Barrier audit: sXs written in reg section of stage s, read in pool of
// stage s+1 -> separated by loc-gemm64's internal __syncthreads. sXs WAR
// (stage s+1 rewrite vs its own pool reads) -> separated by fc-gemm64's
// barrier. sWt/sT1/sT2/sC/sF reuse across stages -> all separated by
// gemm64-internal barriers. sSum is same-thread-only.
// ---------------------------------------------------------------------------
__global__ __launch_bounds__(256) void fused3_kernel(
    const unsigned short* __restrict__ tab0,
    const unsigned short* __restrict__ tab1,
    const unsigned short* __restrict__ tab2,
    const float* __restrict__ prior_xs0, const float* __restrict__ lsgi_w,
    const float* __restrict__ fc_w,  const float* __restrict__ fc_b,
    const float* __restrict__ cls_w, const float* __restrict__ cls_b,
    const float* __restrict__ cls_ow, const float* __restrict__ cls_ob,
    const float* __restrict__ reg_w, const float* __restrict__ reg_b,
    const float* __restrict__ reg_ow, const float* __restrict__ reg_ob,
    const float* __restrict__ loc_w, const float* __restrict__ loc_b,
    const float* __restrict__ loc_ow, const float* __restrict__ loc_ob,
    float* out)
{
    __shared__ __align__(16) float sF [8][68];
    __shared__ __align__(16) float sC [8][68];
    __shared__ __align__(16) float sT1[8][68];
    __shared__ __align__(16) float sT2[8][68];
    __shared__ __align__(16) float sWt[4864];
    __shared__ __align__(16) float sXs[8][72];
    __shared__ __align__(16) float sSum[8][64];

    pool_head_stage<25, 0>(sF, sC, sT1, sT2, sWt, sXs, sSum, tab0, prior_xs0,
                           lsgi_w,
                           fc_w, fc_b, cls_w, cls_b, cls_ow, cls_ob,
                           reg_w, reg_b, reg_ow, reg_ob,
                           loc_w, loc_b, loc_ow, loc_ob,
                           out);
    pool_head_stage<50, 1>(sF, sC, sT1, sT2, sWt, sXs, sSum, tab1, nullptr,
                           lsgi_w + 4096,
                           fc_w, fc_b, cls_w, cls_b, cls_ow, cls_ob,
                           reg_w, reg_b, reg_ow, reg_ob,
                           loc_w, loc_b, loc_ow, loc_ob,
                           out + (size_t)Bq * NPq * OUTD);
    pool_head_stage<100, 2>(sF, sC, sT1, sT2, sWt, sXs, sSum, tab2, nullptr,
                            lsgi_w + 8192,
                            fc_w, fc_b, cls_w, cls_b, cls_ow, cls_ob,
                            reg_w, reg_b, reg_ow, reg_ob,
                            loc_w, loc_b, loc_ow, loc_ob,
                            out + (size_t)2 * Bq * NPq * OUTD);
}

// ---------------------------------------------------------------------------
extern "C" void kernel_launch(void* const* d_in, const int* in_sizes, int n_in,
                              void* d_out, int out_size, void* d_ws, size_t ws_size,
                              hipStream_t stream)
{
    const float* x0        = (const float*)d_in[0];
    const float* x1        = (const float*)d_in[1];
    const float* x2        = (const float*)d_in[2];
    const float* prior_xs0 = (const float*)d_in[3];
    const float* l_weight  = (const float*)d_in[4];
    const float* lsgi_w    = (const float*)d_in[5];
    const float* fc_w      = (const float*)d_in[6];
    const float* fc_b      = (const float*)d_in[7];
    const float* cls_w     = (const float*)d_in[8];
    const float* cls_b     = (const float*)d_in[9];
    const float* cls_ow    = (const float*)d_in[10];
    const float* cls_ob    = (const float*)d_in[11];
    const float* reg_w     = (const float*)d_in[12];
    const float* reg_b     = (const float*)d_in[13];
    const float* reg_ow    = (const float*)d_in[14];
    const float* reg_ob    = (const float*)d_in[15];
    const float* loc_w     = (const float*)d_in[16];
    const float* loc_b     = (const float*)d_in[17];
    const float* loc_ow    = (const float*)d_in[18];
    const float* loc_ob    = (const float*)d_in[19];

    float* out = (float*)d_out;
    unsigned short* tab0 = (unsigned short*)d_ws;
    unsigned short* tab1 = tab0 + (size_t)Bq * NOq * 26  * 64;   // W=25
    unsigned short* tab2 = tab1 + (size_t)Bq * NOq * 51  * 64;   // W=50

    hipLaunchKernelGGL(build_tables_kernel, dim3(3 * Bq * NOq), dim3(256), 0, stream,
                       x2, x1, x0, l_weight, tab0, tab1, tab2);

    hipLaunchKernelGGL(fused3_kernel, dim3(Bq * 24), dim3(256), 0, stream,
                       tab0, tab1, tab2, prior_xs0, lsgi_w,
                       fc_w, fc_b, cls_w, cls_b, cls_ow, cls_ob,
                       reg_w, reg_b, reg_ow, reg_ob,
                       loc_w, loc_b, loc_ow, loc_ob, out);
}

// Round 4
// 242.560 us; speedup vs baseline: 1.3422x; 1.3096x over previous
//
#include <hip/hip_runtime.h>
#include <hip/hip_bf16.h>

#define Bq   32
#define Cq   64
#define NPq  192
#define NOq  72
#define PTS  (NPq * NOq)   // 13824
#define REGD 76
#define OUTD 79

typedef __attribute__((ext_vector_type(8))) short short8;
typedef __attribute__((ext_vector_type(4))) float float4v;

__device__ inline unsigned short f2bf(float x) {
    __hip_bfloat16 h = __float2bfloat16(x);
    return *reinterpret_cast<unsigned short*>(&h);
}

// ---------------------------------------------------------------------------
// Phase 0 (once): build gated y-blended tables for ALL 3 stages.
// EXACT R8 form (measured best; later variants regressed).
// tab[s][b][o][x][c] bf16, x in [0..W] (x=W replicates W-1), c innermost.
// ---------------------------------------------------------------------------
__global__ __launch_bounds__(256) void build_tables_kernel(
    const float* __restrict__ f0,   // x2: H=10,W=25
    const float* __restrict__ f1,   // x1: H=20,W=50
    const float* __restrict__ f2,   // x0: H=40,W=100
    const float* __restrict__ lw,
    unsigned short* __restrict__ t0,
    unsigned short* __restrict__ t1,
    unsigned short* __restrict__ t2)
{
    __shared__ float sRow[64 * 101];

    const int tid = threadIdx.x;
    const int o   = blockIdx.x / 96;
    const int sb  = blockIdx.x - o * 96;
    const int s   = sb >> 5;
    const int b   = sb & 31;

    const float* feat; unsigned short* tab; int H, W;
    if (s == 0)      { feat = f0; tab = t0; H = 10; W = 25; }
    else if (s == 1) { feat = f1; tab = t1; H = 20; W = 50; }
    else             { feat = f2; tab = t2; H = 40; W = 100; }
    const int Wp = W + 1;

    const float ys = 1.0f - (float)o * (1.0f / 71.0f);
    const float iy = ys * (float)(H - 1);
    const float fy = floorf(iy);
    const float wy = iy - fy;
    int iy0 = (int)fy; iy0 = iy0 < 0 ? 0 : (iy0 > H - 1 ? H - 1 : iy0);
    const int iy1 = (iy0 + 1 > H - 1) ? H - 1 : iy0 + 1;
    const float gate = 1.0f / (1.0f + __expf(-lw[o]));

    const float* fb = feat + (size_t)b * 64 * H * W;
    const int iy0W = iy0 * W, iy1W = iy1 * W;

    // blend rows -> LDS [c][x] fp32
    const int tot = 64 * W;
    for (int idx = tid; idx < tot; idx += 256) {
        const int c = idx / W;
        const int x = idx - c * W;
        const float* f = fb + c * (H * W);
        sRow[c * Wp + x] = ((1.0f - wy) * f[iy0W + x] + wy * f[iy1W + x]) * gate;
    }
    __syncthreads();

    // write transposed [x][c] bf16 (c-major coalesced), pad x=W
    unsigned short* to = tab + (size_t)(b * NOq + o) * Wp * 64;
    const int tot2 = Wp * 64;
    for (int idx = tid; idx < tot2; idx += 256) {
        const int x = idx >> 6;
        const int c = idx & 63;
        const int xx = (x < W) ? x : (W - 1);
        to[idx] = f2bf(sRow[c * Wp + xx]);
    }
}

// ---------------------------------------------------------------------------
// Fused: table gather + MFMA pool (verbatim R0/R8 form, measured best) +
// R13 HEAD: wave-per-point, barrier-free.
//  - wave w owns points {w, w+4}; per-point LDS ping-pong buffers are
//    single-wave-private -> in-order DS pipe gives RAW ordering, no barriers
//  - lane = output column; activations via float4 LDS broadcast; weights
//    coalesced 256B rows from global (waves stay layer-synced -> 16KB
//    working set, L1-resident; 16-deep unrolled independent loads hide lat)
//  - only ONE __syncthreads (after pool publishes sF cross-wave)
// ---------------------------------------------------------------------------
template<int W>
__global__ __launch_bounds__(256) void fused_pool_head_kernel(
    const unsigned short* __restrict__ tab,   // [B][72][W+1][64] bf16
    const float* __restrict__ xsrc, const int xstride,
    const float* __restrict__ lsgi,           // [64][64] this stage
    float* __restrict__ sumFeat,              // [B*NP][64]
    const int stage,
    const float* __restrict__ fc_w,  const float* __restrict__ fc_b,
    const float* __restrict__ cls_w, const float* __restrict__ cls_b,
    const float* __restrict__ cls_ow, const float* __restrict__ cls_ob,
    const float* __restrict__ reg_w, const float* __restrict__ reg_b,
    const float* __restrict__ reg_ow, const float* __restrict__ reg_ob,
    const float* __restrict__ loc_w, const float* __restrict__ loc_b,
    const float* __restrict__ loc_ow, const float* __restrict__ loc_ob,
    float* __restrict__ out, float* __restrict__ xs_next)
{
    constexpr int Wp = W + 1;
    __shared__ __align__(16) float sF  [8][68];
    __shared__ __align__(16) float bufC[8][64];
    __shared__ __align__(16) float bufA[8][64];
    __shared__ __align__(16) float bufB[8][64];

    const int tid  = threadIdx.x;
    const int w    = tid >> 6;
    const int lane = tid & 63;
    const int ng   = blockIdx.x >> 5;         // 0..23
    const int b    = blockIdx.x & 31;
    const int npair = ng * 4 + w;             // 0..95

    // ---------------- pool (verbatim R0) ----------------
    short8 wf[4][2];
    {
        const int kb = ((lane >> 4) & 3) * 8;
        const int dl = lane & 15;
        #pragma unroll
        for (int ks = 0; ks < 2; ++ks)
            #pragma unroll
            for (int dt = 0; dt < 4; ++dt) {
                union { unsigned short u[8]; short8 v; } pk;
                #pragma unroll
                for (int j = 0; j < 8; ++j)
                    pk.u[j] = f2bf(lsgi[(ks * 32 + kb + j) * 64 + dt * 16 + dl]);
                wf[dt][ks] = pk.v;
            }
    }

    const unsigned short* tb = tab + (size_t)b * NOq * Wp * 64;
    const float* xp = xsrc + (size_t)xstride * b;
    const int m  = lane & 15;
    const int kg = lane >> 4;
    const int nt0 = npair * 9;

    float sums0[4] = {0.f, 0.f, 0.f, 0.f};
    float sums1[4] = {0.f, 0.f, 0.f, 0.f};

    #pragma unroll
    for (int ntl = 0; ntl < 9; ++ntl) {
        const int pt = (nt0 + ntl) * 16 + m;
        const int o  = pt % NOq;
        float ixf = xp[pt] * (float)(W - 1);
        ixf = fminf(fmaxf(ixf, 0.0f), (float)(W - 1));
        const float fx = floorf(ixf);
        const float wx = ixf - fx;
        const int ix0 = (int)fx;

        const unsigned short* col = tb + ((size_t)o * Wp + ix0) * 64 + kg * 8;
        const short8 a00 = *(const short8*)(col);        // tap0, k-lo
        const short8 a01 = *(const short8*)(col + 64);   // tap1, k-lo
        const short8 a10 = *(const short8*)(col + 32);   // tap0, k-hi
        const short8 a11 = *(const short8*)(col + 96);   // tap1, k-hi

        // per-C-row wx (rows kg*4 .. kg*4+3 of this tile)
        float wxr[4];
        #pragma unroll
        for (int j = 0; j < 4; ++j) wxr[j] = __shfl(wx, kg * 4 + j);

        const bool hi = (ntl * 16 + (kg * 4)) >= NOq;
        #pragma unroll
        for (int dt = 0; dt < 4; ++dt) {
            float4v c0 = {0.f, 0.f, 0.f, 0.f};
            float4v c1 = {0.f, 0.f, 0.f, 0.f};
            c0 = __builtin_amdgcn_mfma_f32_16x16x32_bf16(a00, wf[dt][0], c0, 0, 0, 0);
            c0 = __builtin_amdgcn_mfma_f32_16x16x32_bf16(a10, wf[dt][1], c0, 0, 0, 0);
            c1 = __builtin_amdgcn_mfma_f32_16x16x32_bf16(a01, wf[dt][0], c1, 0, 0, 0);
            c1 = __builtin_amdgcn_mfma_f32_16x16x32_bf16(a11, wf[dt][1], c1, 0, 0, 0);
            const float v0 = c0[0] + wxr[0] * (c1[0] - c0[0]);
            const float v1 = c0[1] + wxr[1] * (c1[1] - c0[1]);
            const float v2 = c0[2] + wxr[2] * (c1[2] - c0[2]);
            const float v3 = c0[3] + wxr[3] * (c1[3] - c0[3]);
            const float pm0 = fmaxf(fmaxf(v0, v1), 0.f);
            const float pm1 = fmaxf(fmaxf(v2, v3), 0.f);
            const float add = pm0 + pm1;
            if (hi) sums1[dt] += add; else sums0[dt] += add;
        }
    }

    #pragma unroll
    for (int dt = 0; dt < 4; ++dt) {
        float v0 = sums0[dt], v1 = sums1[dt];
        v0 += __shfl_xor(v0, 16); v0 += __shfl_xor(v0, 32);
        v1 += __shfl_xor(v1, 16); v1 += __shfl_xor(v1, 32);
        sums0[dt] = v0; sums1[dt] = v1;
    }

    const float invS = 1.0f / (float)(stage + 1);
    if (lane < 16) {
        const size_t row0 = (size_t)(b * NPq + npair * 2) * 64;
        #pragma unroll
        for (int dt = 0; dt < 4; ++dt) {
            const int d = dt * 16 + lane;
            float t0 = sums0[dt] * (1.0f / 36.0f);
            float t1 = sums1[dt] * (1.0f / 36.0f);
            float* p0 = sumFeat + row0 + d;
            float* p1 = sumFeat + row0 + 64 + d;
            if (stage > 0) { t0 += *p0; t1 += *p1; }
            *p0 = t0; *p1 = t1;
            sF[2 * w][d]     = t0 * invS;
            sF[2 * w + 1][d] = t1 * invS;
        }
    }
    __syncthreads();   // sF published cross-wave; ONLY barrier in the head

    // ---------------- head: wave-per-point, barrier-free ----------------
    const int pA  = w;
    const int pB  = w + 4;
    const int p0g = b * NPq + ng * 8;  // global point base

    auto layer = [&](const float* iA, const float* iB, float* oA, float* oB,
                     const float* __restrict__ gw, const float* __restrict__ gb) {
        const float bias = gb[lane];
        float accA = bias, accB = bias;
        #pragma unroll 4
        for (int k = 0; k < 64; k += 4) {
            const float4 a4 = *(const float4*)(iA + k);   // LDS broadcast
            const float4 b4 = *(const float4*)(iB + k);
            const float w0 = gw[(k + 0) * 64 + lane];     // coalesced 256B row
            const float w1 = gw[(k + 1) * 64 + lane];
            const float w2 = gw[(k + 2) * 64 + lane];
            const float w3 = gw[(k + 3) * 64 + lane];
            accA += a4.x * w0 + a4.y * w1 + a4.z * w2 + a4.w * w3;
            accB += b4.x * w0 + b4.y * w1 + b4.z * w2 + b4.w * w3;
        }
        oA[lane] = fmaxf(accA, 0.f);
        oB[lane] = fmaxf(accB, 0.f);
        __builtin_amdgcn_wave_barrier();   // compile-time fence (same-wave DS is in-order)
    };

    // fc
    layer(sF[pA], sF[pB], bufC[pA], bufC[pB], fc_w, fc_b);

    // ---- cls ----
    layer(bufC[pA], bufC[pB], bufA[pA], bufA[pB], cls_w,        cls_b);
    layer(bufA[pA], bufA[pB], bufB[pA], bufB[pB], cls_w + 4096, cls_b + 64);
    {
        const float bA = bufB[pA][lane], bB = bufB[pB][lane];
        const float2 ow = *(const float2*)&cls_ow[lane * 2];
        float v0 = bA * ow.x, v1 = bA * ow.y;
        float v2 = bB * ow.x, v3 = bB * ow.y;
        #pragma unroll
        for (int m2 = 1; m2 < 64; m2 <<= 1) {
            v0 += __shfl_xor(v0, m2);
            v1 += __shfl_xor(v1, m2);
            v2 += __shfl_xor(v2, m2);
            v3 += __shfl_xor(v3, m2);
        }
        if (lane == 0) {
            out[(size_t)(p0g + pA) * OUTD + 0] = v0 + cls_ob[0];
            out[(size_t)(p0g + pA) * OUTD + 1] = v1 + cls_ob[1];
            out[(size_t)(p0g + pB) * OUTD + 0] = v2 + cls_ob[0];
            out[(size_t)(p0g + pB) * OUTD + 1] = v3 + cls_ob[1];
        }
    }

    // ---- reg ----
    layer(bufC[pA], bufC[pB], bufA[pA], bufA[pB], reg_w,        reg_b);
    layer(bufA[pA], bufA[pB], bufB[pA], bufB[pB], reg_w + 4096, reg_b + 64);
    {
        const int j1 = lane;                              // 0..63
        const int j2 = (lane < 12) ? 64 + lane : 75;      // clamped (in-bounds loads)
        float zA1 = reg_ob[j1], zB1 = zA1;
        float zA2 = reg_ob[j2], zB2 = zA2;
        #pragma unroll 4
        for (int k = 0; k < 64; k += 4) {
            const float4 a4 = *(const float4*)&bufB[pA][k];
            const float4 b4 = *(const float4*)&bufB[pB][k];
            const float u0 = reg_ow[(k + 0) * REGD + j1];
            const float u1 = reg_ow[(k + 1) * REGD + j1];
            const float u2 = reg_ow[(k + 2) * REGD + j1];
            const float u3 = reg_ow[(k + 3) * REGD + j1];
            const float t0 = reg_ow[(k + 0) * REGD + j2];
            const float t1 = reg_ow[(k + 1) * REGD + j2];
            const float t2 = reg_ow[(k + 2) * REGD + j2];
            const float t3 = reg_ow[(k + 3) * REGD + j2];
            zA1 += a4.x * u0 + a4.y * u1 + a4.z * u2 + a4.w * u3;
            zB1 += b4.x * u0 + b4.y * u1 + b4.z * u2 + b4.w * u3;
            zA2 += a4.x * t0 + a4.y * t1 + a4.z * t2 + a4.w * t3;
            zB2 += b4.x * t0 + b4.y * t1 + b4.z * t2 + b4.w * t3;
        }
        float* orA = out + (size_t)(p0g + pA) * OUTD;
        float* orB = out + (size_t)(p0g + pB) * OUTD;
        float* xsA = xs_next + (size_t)(p0g + pA) * NOq;
        float* xsB = xs_next + (size_t)(p0g + pB) * NOq;
        orA[2 + j1] = zA1;
        orB[2 + j1] = zB1;
        if (lane >= 4) {
            xsA[j1 - 4] = 1.0f / (1.0f + __expf(-zA1));
            xsB[j1 - 4] = 1.0f / (1.0f + __expf(-zB1));
        }
        if (lane < 12) {
            orA[2 + j2] = zA2;
            orB[2 + j2] = zB2;
            xsA[j2 - 4] = 1.0f / (1.0f + __expf(-zA2));
            xsB[j2 - 4] = 1.0f / (1.0f + __expf(-zB2));
        }
    }

    // ---- loc ----
    layer(bufC[pA], bufC[pB], bufA[pA], bufA[pB], loc_w,        loc_b);
    layer(bufA[pA], bufA[pB], bufB[pA], bufB[pB], loc_w + 4096, loc_b + 64);
    {
        float v0 = bufB[pA][lane] * loc_ow[lane];
        float v1 = bufB[pB][lane] * loc_ow[lane];
        #pragma unroll
        for (int m2 = 1; m2 < 64; m2 <<= 1) {
            v0 += __shfl_xor(v0, m2);
            v1 += __shfl_xor(v1, m2);
        }
        if (lane == 0) {
            out[(size_t)(p0g + pA) * OUTD + 78] = v0 + loc_ob[0];
            out[(size_t)(p0g + pB) * OUTD + 78] = v1 + loc_ob[0];
        }
    }
}

// ---------------------------------------------------------------------------
extern "C" void kernel_launch(void* const* d_in, const int* in_sizes, int n_in,
                              void* d_out, int out_size, void* d_ws, size_t ws_size,
                              hipStream_t stream)
{
    const float* x0        = (const float*)d_in[0];
    const float* x1        = (const float*)d_in[1];
    const float* x2        = (const float*)d_in[2];
    const float* prior_xs0 = (const float*)d_in[3];
    const float* l_weight  = (const float*)d_in[4];
    const float* lsgi_w    = (const float*)d_in[5];
    const float* fc_w      = (const float*)d_in[6];
    const float* fc_b      = (const float*)d_in[7];
    const float* cls_w     = (const float*)d_in[8];
    const float* cls_b     = (const float*)d_in[9];
    const float* cls_ow    = (const float*)d_in[10];
    const float* cls_ob    = (const float*)d_in[11];
    const float* reg_w     = (const float*)d_in[12];
    const float* reg_b     = (const float*)d_in[13];
    const float* reg_ow    = (const float*)d_in[14];
    const float* reg_ob    = (const float*)d_in[15];
    const float* loc_w     = (const float*)d_in[16];
    const float* loc_b     = (const float*)d_in[17];
    const float* loc_ow    = (const float*)d_in[18];
    const float* loc_ob    = (const float*)d_in[19];

    float* out     = (float*)d_out;
    float* sumFeat = (float*)d_ws;                               // [6144][64] f32
    float* xs      = sumFeat + (size_t)Bq * NPq * Cq;            // [6144][72] f32
    unsigned short* tab0 = (unsigned short*)(xs + (size_t)Bq * PTS);
    unsigned short* tab1 = tab0 + (size_t)Bq * NOq * 26  * 64;   // W=25
    unsigned short* tab2 = tab1 + (size_t)Bq * NOq * 51  * 64;   // W=50

    hipLaunchKernelGGL(build_tables_kernel, dim3(3 * Bq * NOq), dim3(256), 0, stream,
                       x2, x1, x0, l_weight, tab0, tab1, tab2);

    for (int s = 0; s < 3; ++s) {
        const float* xsrc = (s == 0) ? prior_xs0 : xs;
        const int xstr    = (s == 0) ? 0 : PTS;
        const unsigned short* tb = (s == 0) ? tab0 : (s == 1) ? tab1 : tab2;
        float* outS = out + (size_t)s * Bq * NPq * OUTD;
        if (s == 0)
            hipLaunchKernelGGL((fused_pool_head_kernel<25>), dim3(Bq * 24), dim3(256), 0, stream,
                               tb, xsrc, xstr, lsgi_w + s * 4096, sumFeat, s,
                               fc_w, fc_b, cls_w, cls_b, cls_ow, cls_ob,
                               reg_w, reg_b, reg_ow, reg_ob,
                               loc_w, loc_b, loc_ow, loc_ob, outS, xs);
        else if (s == 1)
            hipLaunchKernelGGL((fused_pool_head_kernel<50>), dim3(Bq * 24), dim3(256), 0, stream,
                               tb, xsrc, xstr, lsgi_w + s * 4096, sumFeat, s,
                               fc_w, fc_b, cls_w, cls_b, cls_ow, cls_ob,
                               reg_w, reg_b, reg_ow, reg_ob,
                               loc_w, loc_b, loc_ow, loc_ob, outS, xs);
        else
            hipLaunchKernelGGL((fused_pool_head_kernel<100>), dim3(Bq * 24), dim3(256), 0, stream,
                               tb, xsrc, xstr, lsgi_w + s * 4096, sumFeat, s,
                               fc_w, fc_b, cls_w, cls_b, cls_ow, cls_ob,
                               reg_w, reg_b, reg_ow, reg_ob,
                               loc_w, loc_b, loc_ow, loc_ob, outS, xs);
    }
}